// Round 4
// baseline (1441.176 us; speedup 1.0000x reference)
//
#include <hip/hip_runtime.h>
#include <math.h>

#define NN 4096
#define FF 256
#define RR 8
#define BQ 16384

typedef _Float16 half_t;
typedef half_t v8h __attribute__((ext_vector_type(8)));
typedef float  v4f __attribute__((ext_vector_type(4)));

// G values are scaled by 1/64 before the fp16 split (layer-2 G reaches ~1.2e5,
// fp16 max = 65504); gemm_ag epilogue multiplies the 64 back in.
#define G_SCALE     0.015625f
#define G_SCALE_INV 64.0f

// ---------------------------------------------------------------------------
// Kernel 1: G[r] = H @ W[r]^T, written TRANSPOSED and SPLIT to fp16 hi/lo:
//   Ght/Glt layout [r][f][m] (k-contiguous for the gemm_ag B-fragment reads).
// (verbatim from hardware-verified round-1 kernel)
// ---------------------------------------------------------------------------
__global__ __launch_bounds__(256) void gemm_g(const float* __restrict__ H,
                                              const float* __restrict__ W,
                                              half_t* __restrict__ Ght,
                                              half_t* __restrict__ Glt) {
    __shared__ float smem[2 * 32 * 68];           // 17408 B, reused by epilogue
    float (*Hs)[68] = (float(*)[68])smem;         // [k][m-row]
    float (*Ws)[68] = (float(*)[68])(smem + 2176);// [k][f-row]

    const int tid = threadIdx.x;
    const int r   = blockIdx.z;
    const int o0  = blockIdx.x * 64;   // f
    const int m0  = blockIdx.y * 64;   // m
    const int tx  = tid & 15;
    const int ty  = tid >> 4;

    const float* __restrict__ Wr = W + (size_t)r * FF * FF;

    const int lr = tid >> 2;        // row 0..63
    const int lc = (tid & 3) * 8;   // k offset 0,8,16,24

    float acc[4][4];
#pragma unroll
    for (int i = 0; i < 4; ++i)
#pragma unroll
        for (int j = 0; j < 4; ++j) acc[i][j] = 0.0f;

    for (int fb = 0; fb < FF; fb += 32) {
        float4 h0 = *(const float4*)&H[(size_t)(m0 + lr) * FF + fb + lc];
        float4 h1 = *(const float4*)&H[(size_t)(m0 + lr) * FF + fb + lc + 4];
        float4 w0 = *(const float4*)&Wr[(size_t)(o0 + lr) * FF + fb + lc];
        float4 w1 = *(const float4*)&Wr[(size_t)(o0 + lr) * FF + fb + lc + 4];

        __syncthreads();
        Hs[lc + 0][lr] = h0.x;  Hs[lc + 1][lr] = h0.y;
        Hs[lc + 2][lr] = h0.z;  Hs[lc + 3][lr] = h0.w;
        Hs[lc + 4][lr] = h1.x;  Hs[lc + 5][lr] = h1.y;
        Hs[lc + 6][lr] = h1.z;  Hs[lc + 7][lr] = h1.w;
        Ws[lc + 0][lr] = w0.x;  Ws[lc + 1][lr] = w0.y;
        Ws[lc + 2][lr] = w0.z;  Ws[lc + 3][lr] = w0.w;
        Ws[lc + 4][lr] = w1.x;  Ws[lc + 5][lr] = w1.y;
        Ws[lc + 6][lr] = w1.z;  Ws[lc + 7][lr] = w1.w;
        __syncthreads();

#pragma unroll
        for (int k = 0; k < 32; ++k) {
            float4 hv = *(const float4*)&Hs[k][ty * 4];
            float4 wv = *(const float4*)&Ws[k][tx * 4];
            float a[4] = {hv.x, hv.y, hv.z, hv.w};
            float b[4] = {wv.x, wv.y, wv.z, wv.w};
#pragma unroll
            for (int i = 0; i < 4; ++i)
#pragma unroll
                for (int j = 0; j < 4; ++j) acc[i][j] += a[i] * b[j];
        }
    }

    // ---- epilogue: transpose tile through LDS, split to fp16 hi/lo ----
    __syncthreads();                       // main-loop reads of Hs/Ws done
    float (*T)[65] = (float(*)[65])smem;   // [m_local][f_local]
#pragma unroll
    for (int i = 0; i < 4; ++i)
#pragma unroll
        for (int j = 0; j < 4; ++j)
            T[ty * 4 + i][tx * 4 + j] = acc[i][j] * G_SCALE;
    __syncthreads();

    const int fr = tid >> 2;          // f_local 0..63
    const int mc = (tid & 3) << 4;    // m_local chunk 0,16,32,48
    v8h h0, h1, l0, l1;
#pragma unroll
    for (int q = 0; q < 8; ++q) {
        float v = T[mc + q][fr];
        half_t hh = (half_t)v;
        h0[q] = hh;
        l0[q] = (half_t)(v - (float)hh);
    }
#pragma unroll
    for (int q = 0; q < 8; ++q) {
        float v = T[mc + 8 + q][fr];
        half_t hh = (half_t)v;
        h1[q] = hh;
        l1[q] = (half_t)(v - (float)hh);
    }
    const size_t off = ((size_t)r * FF + o0 + fr) * NN + m0 + mc;
    *(v8h*)(Ght + off)     = h0;
    *(v8h*)(Ght + off + 8) = h1;
    *(v8h*)(Glt + off)     = l0;
    *(v8h*)(Glt + off + 8) = l1;
}

// ---------------------------------------------------------------------------
// Kernel 1.5 (fast path only): pre-split A fp32 -> Ah/Al fp16, once.
// Plain elementwise streaming kernel, fully bounded.
// ---------------------------------------------------------------------------
__global__ __launch_bounds__(256) void split_a(const float* __restrict__ A,
                                               half_t* __restrict__ Ah,
                                               half_t* __restrict__ Al) {
    const size_t total  = (size_t)RR * NN * NN / 8;   // groups of 8 floats
    const size_t stride = (size_t)gridDim.x * 256;
    for (size_t g = (size_t)blockIdx.x * 256 + threadIdx.x; g < total; g += stride) {
        const float* src = A + g * 8;
        float4 f0 = *(const float4*)(src);
        float4 f1 = *(const float4*)(src + 4);
        float av[8] = {f0.x, f0.y, f0.z, f0.w, f1.x, f1.y, f1.z, f1.w};
        v8h h, l;
#pragma unroll
        for (int e = 0; e < 8; ++e) {
            half_t hh = (half_t)av[e];
            h[e] = hh;
            l[e] = (half_t)(av[e] - (float)hh);
        }
        *(v8h*)(Ah + g * 8) = h;
        *(v8h*)(Al + g * 8) = l;
    }
}

// ---------------------------------------------------------------------------
// Kernel 2 FAST (reg-staged, NO global_load_lds — bisect vs rounds 2/3):
// P[plane] = c[r] * (A[r] @ G[r]) over one K-half, pure fp16 MFMA.
// Structure is the hardware-verified round-1 loop (reg prefetch -> LDS ->
// 48 MFMA/wave) minus the in-loop fp32->fp16 split (A is pre-split).
// Tile 128x128, BK=32, 4 waves (2x2), K split 2-way -> 16 P planes.
// Grid 1024; XCD swizzle: r = bid&7; f-pairs adjacent for A-panel L2 reuse.
// LDS rows padded to 40 halves (80 B) -> 2-way bank aliasing only (free).
// ---------------------------------------------------------------------------
__global__ __launch_bounds__(256, 3) void gemm_ag_fast(const half_t* __restrict__ Ah,
                                                       const half_t* __restrict__ Al,
                                                       const half_t* __restrict__ Ght,
                                                       const half_t* __restrict__ Glt,
                                                       const float* __restrict__ c,
                                                       float* __restrict__ P) {
    __shared__ half_t S[4][128][40];   // Ah, Al, Bh, Bl tiles; 40960 B

    const int tid = threadIdx.x;
    const int bid = blockIdx.x;            // 0..1023
    const int r   = bid & 7;               // one r per XCD
    const int pos = bid >> 3;              // 0..127
    const int fb  = pos & 1;               // f block (pairs adjacent -> A L2 reuse)
    const int kh  = (pos >> 1) & 1;        // K half
    const int mb  = pos >> 2;              // 0..31
    const int m0  = mb * 128;
    const int f0  = fb * 128;
    const int k0  = kh * (NN / 2);

    // ---- staging geometry: thread = (row, 16-half chunk); 2 v8h per panel ----
    const int srow  = tid >> 1;        // 0..127
    const int skoff = (tid & 1) * 16;  // 0 or 16 halves

    const half_t* __restrict__ g0 = Ah  + ((size_t)r * NN + m0 + srow) * NN + k0 + skoff;
    const half_t* __restrict__ g1 = Al  + ((size_t)r * NN + m0 + srow) * NN + k0 + skoff;
    const half_t* __restrict__ g2 = Ght + ((size_t)r * FF + f0 + srow) * NN + k0 + skoff;
    const half_t* __restrict__ g3 = Glt + ((size_t)r * FF + f0 + srow) * NN + k0 + skoff;

    // ---- compute geometry: 2x2 waves, each 64x64; 16x16x32 f16 frags ----
    const int wid  = tid >> 6;
    const int lane = tid & 63;
    const int wr   = wid >> 1;
    const int wc   = wid & 1;
    const int lrow = lane & 15;
    const int lk8  = (lane >> 4) * 8;

    v4f acc[4][4];
#pragma unroll
    for (int m = 0; m < 4; ++m)
#pragma unroll
        for (int n = 0; n < 4; ++n) acc[m][n] = (v4f){0.f, 0.f, 0.f, 0.f};

    // prefetch K-tile 0 into registers (8 x 16B loads)
    v8h p00 = *(const v8h*)(g0);     v8h p01 = *(const v8h*)(g0 + 8);
    v8h p10 = *(const v8h*)(g1);     v8h p11 = *(const v8h*)(g1 + 8);
    v8h p20 = *(const v8h*)(g2);     v8h p21 = *(const v8h*)(g2 + 8);
    v8h p30 = *(const v8h*)(g3);     v8h p31 = *(const v8h*)(g3 + 8);

    for (int kb = 0; kb < NN / 2; kb += 32) {
        __syncthreads();   // previous tile's LDS reads complete
        *(v8h*)&S[0][srow][skoff]     = p00;
        *(v8h*)&S[0][srow][skoff + 8] = p01;
        *(v8h*)&S[1][srow][skoff]     = p10;
        *(v8h*)&S[1][srow][skoff + 8] = p11;
        *(v8h*)&S[2][srow][skoff]     = p20;
        *(v8h*)&S[2][srow][skoff + 8] = p21;
        *(v8h*)&S[3][srow][skoff]     = p30;
        *(v8h*)&S[3][srow][skoff + 8] = p31;
        __syncthreads();

        if (kb + 32 < NN / 2) {   // prefetch next tile while computing this one
            const int kn = kb + 32;
            p00 = *(const v8h*)(g0 + kn);     p01 = *(const v8h*)(g0 + kn + 8);
            p10 = *(const v8h*)(g1 + kn);     p11 = *(const v8h*)(g1 + kn + 8);
            p20 = *(const v8h*)(g2 + kn);     p21 = *(const v8h*)(g2 + kn + 8);
            p30 = *(const v8h*)(g3 + kn);     p31 = *(const v8h*)(g3 + kn + 8);
        }

        v8h bh[4], bl[4];
#pragma unroll
        for (int n = 0; n < 4; ++n) {
            const int bc = wc * 64 + n * 16 + lrow;
            bh[n] = *(const v8h*)&S[2][bc][lk8];
            bl[n] = *(const v8h*)&S[3][bc][lk8];
        }
#pragma unroll
        for (int m = 0; m < 4; ++m) {
            const int ar = wr * 64 + m * 16 + lrow;
            v8h ahf = *(const v8h*)&S[0][ar][lk8];
            v8h alf = *(const v8h*)&S[1][ar][lk8];
#pragma unroll
            for (int n = 0; n < 4; ++n) {
                acc[m][n] = __builtin_amdgcn_mfma_f32_16x16x32_f16(alf, bh[n], acc[m][n], 0, 0, 0);
                acc[m][n] = __builtin_amdgcn_mfma_f32_16x16x32_f16(ahf, bl[n], acc[m][n], 0, 0, 0);
                acc[m][n] = __builtin_amdgcn_mfma_f32_16x16x32_f16(ahf, bh[n], acc[m][n], 0, 0, 0);
            }
        }
    }

    // ---- epilogue: scale by c[r,m] * 64, store plane (r*2 + kh) ----
    // C/D layout (m89-verified): col = lane&15, row = (lane>>4)*4 + j
    float* __restrict__ Pp = P + (size_t)(r * 2 + kh) * NN * FF;
#pragma unroll
    for (int m = 0; m < 4; ++m) {
        const int gm0 = m0 + wr * 64 + m * 16 + ((lane >> 4) << 2);
        float cv[4];
#pragma unroll
        for (int j = 0; j < 4; ++j)
            cv[j] = c[r * NN + gm0 + j] * G_SCALE_INV;
#pragma unroll
        for (int n = 0; n < 4; ++n) {
            const int gf = f0 + wc * 64 + n * 16 + (lane & 15);
#pragma unroll
            for (int j = 0; j < 4; ++j)
                Pp[(size_t)(gm0 + j) * FF + gf] = acc[m][n][j] * cv[j];
        }
    }
}

// ---------------------------------------------------------------------------
// Kernel 2 FALLBACK (verbatim verified round-1): in-loop A split, reg staging.
// ---------------------------------------------------------------------------
__global__ __launch_bounds__(256, 2) void gemm_ag(const float* __restrict__ A,
                                                  const half_t* __restrict__ Ght,
                                                  const half_t* __restrict__ Glt,
                                                  const float* __restrict__ c,
                                                  float* __restrict__ P) {
    __shared__ half_t Ahs[128][40];
    __shared__ half_t Als[128][40];
    __shared__ half_t Bhs[128][40];
    __shared__ half_t Bls[128][40];

    const int tid = threadIdx.x;
    const int r   = blockIdx.z;
    const int f0  = blockIdx.x * 128;
    const int m0  = blockIdx.y * 128;

    const float*  __restrict__ Ar  = A   + (size_t)r * NN * NN;
    const half_t* __restrict__ BhG = Ght + ((size_t)r * FF + f0) * NN;
    const half_t* __restrict__ BlG = Glt + ((size_t)r * FF + f0) * NN;

    const int srow  = tid >> 1;
    const int skoff = (tid & 1) * 16;

    const int wid  = tid >> 6;
    const int lane = tid & 63;
    const int wr   = wid >> 1;
    const int wc   = wid & 1;
    const int lrow = lane & 15;
    const int lk   = (lane >> 4) * 8;

    v4f acc[4][4];
#pragma unroll
    for (int m = 0; m < 4; ++m)
#pragma unroll
        for (int n = 0; n < 4; ++n) acc[m][n] = (v4f){0.f, 0.f, 0.f, 0.f};

    const float*  Arow  = Ar  + (size_t)(m0 + srow) * NN;
    const half_t* Bhrow = BhG + (size_t)srow * NN;
    const half_t* Blrow = BlG + (size_t)srow * NN;

    float4 pa0 = *(const float4*)(Arow + skoff);
    float4 pa1 = *(const float4*)(Arow + skoff + 4);
    float4 pa2 = *(const float4*)(Arow + skoff + 8);
    float4 pa3 = *(const float4*)(Arow + skoff + 12);
    float4 pbh0 = *(const float4*)(Bhrow + skoff);
    float4 pbh1 = *(const float4*)(Bhrow + skoff + 8);
    float4 pbl0 = *(const float4*)(Blrow + skoff);
    float4 pbl1 = *(const float4*)(Blrow + skoff + 8);

    for (int kb = 0; kb < NN; kb += 32) {
        __syncthreads();
        {
            float av[16];
            *(float4*)(av + 0)  = pa0;
            *(float4*)(av + 4)  = pa1;
            *(float4*)(av + 8)  = pa2;
            *(float4*)(av + 12) = pa3;
            v8h h0, h1, l0, l1;
#pragma unroll
            for (int e = 0; e < 8; ++e) {
                half_t hh = (half_t)av[e];
                h0[e] = hh;
                l0[e] = (half_t)(av[e] - (float)hh);
            }
#pragma unroll
            for (int e = 0; e < 8; ++e) {
                half_t hh = (half_t)av[8 + e];
                h1[e] = hh;
                l1[e] = (half_t)(av[8 + e] - (float)hh);
            }
            *(v8h*)&Ahs[srow][skoff]     = h0;
            *(v8h*)&Ahs[srow][skoff + 8] = h1;
            *(v8h*)&Als[srow][skoff]     = l0;
            *(v8h*)&Als[srow][skoff + 8] = l1;
            *(float4*)&Bhs[srow][skoff]     = pbh0;
            *(float4*)&Bhs[srow][skoff + 8] = pbh1;
            *(float4*)&Bls[srow][skoff]     = pbl0;
            *(float4*)&Bls[srow][skoff + 8] = pbl1;
        }
        __syncthreads();

        if (kb + 32 < NN) {
            const int kn = kb + 32;
            pa0 = *(const float4*)(Arow + kn + skoff);
            pa1 = *(const float4*)(Arow + kn + skoff + 4);
            pa2 = *(const float4*)(Arow + kn + skoff + 8);
            pa3 = *(const float4*)(Arow + kn + skoff + 12);
            pbh0 = *(const float4*)(Bhrow + kn + skoff);
            pbh1 = *(const float4*)(Bhrow + kn + skoff + 8);
            pbl0 = *(const float4*)(Blrow + kn + skoff);
            pbl1 = *(const float4*)(Blrow + kn + skoff + 8);
        }

        v8h bh[4], bl[4];
#pragma unroll
        for (int n = 0; n < 4; ++n) {
            const int bc = wc * 64 + n * 16 + lrow;
            bh[n] = *(const v8h*)&Bhs[bc][lk];
            bl[n] = *(const v8h*)&Bls[bc][lk];
        }
#pragma unroll
        for (int m = 0; m < 4; ++m) {
            const int ar = wr * 64 + m * 16 + lrow;
            v8h ahf = *(const v8h*)&Ahs[ar][lk];
            v8h alf = *(const v8h*)&Als[ar][lk];
#pragma unroll
            for (int n = 0; n < 4; ++n) {
                acc[m][n] = __builtin_amdgcn_mfma_f32_16x16x32_f16(alf, bh[n], acc[m][n], 0, 0, 0);
                acc[m][n] = __builtin_amdgcn_mfma_f32_16x16x32_f16(ahf, bl[n], acc[m][n], 0, 0, 0);
                acc[m][n] = __builtin_amdgcn_mfma_f32_16x16x32_f16(ahf, bh[n], acc[m][n], 0, 0, 0);
            }
        }
    }

    float* __restrict__ Pp = P + (size_t)r * NN * FF;
#pragma unroll
    for (int m = 0; m < 4; ++m) {
        const int gm0 = m0 + wr * 64 + m * 16 + ((lane >> 4) << 2);
        float cv[4];
#pragma unroll
        for (int j = 0; j < 4; ++j)
            cv[j] = c[r * NN + gm0 + j] * G_SCALE_INV;
#pragma unroll
        for (int n = 0; n < 4; ++n) {
            const int gf = f0 + wc * 64 + n * 16 + (lane & 15);
#pragma unroll
            for (int j = 0; j < 4; ++j)
                Pp[(size_t)(gm0 + j) * FF + gf] = acc[m][n][j] * cv[j];
        }
    }
}

// ---------------------------------------------------------------------------
// Kernel 3: Hout = sum over np planes of P
// ---------------------------------------------------------------------------
__global__ __launch_bounds__(256) void reduce_p(const float* __restrict__ P,
                                                float* __restrict__ Hout,
                                                int np) {
    const size_t idx = ((size_t)blockIdx.x * 256 + threadIdx.x) * 4;
    float4 s = *(const float4*)&P[idx];
    for (int r = 1; r < np; ++r) {
        float4 v = *(const float4*)&P[(size_t)r * NN * FF + idx];
        s.x += v.x; s.y += v.y; s.z += v.z; s.w += v.w;
    }
    *(float4*)&Hout[idx] = s;
}

// ---------------------------------------------------------------------------
// Kernel 4: score[b] = sigmoid( sum_f E1[b,f] * Mdiag[rel[b],f] * E2[b,f] )
// ---------------------------------------------------------------------------
__global__ __launch_bounds__(256) void score_k(const float* __restrict__ H2,
                                               const float* __restrict__ relm,
                                               const int* __restrict__ e1,
                                               const int* __restrict__ rel,
                                               const int* __restrict__ e2,
                                               float* __restrict__ out) {
    const int wave = threadIdx.x >> 6;
    const int lane = threadIdx.x & 63;
    const int b = blockIdx.x * 4 + wave;
    if (b >= BQ) return;

    const int rr = rel[b];
    const float4* __restrict__ x = (const float4*)(H2 + (size_t)e1[b] * FF);
    const float4* __restrict__ y = (const float4*)(H2 + (size_t)e2[b] * FF);
    const float* __restrict__ M = relm + (size_t)rr * FF * FF;

    float4 xv = x[lane];
    float4 yv = y[lane];
    const int f = lane * 4;
    float s = xv.x * yv.x * M[(size_t)(f + 0) * (FF + 1)]
            + xv.y * yv.y * M[(size_t)(f + 1) * (FF + 1)]
            + xv.z * yv.z * M[(size_t)(f + 2) * (FF + 1)]
            + xv.w * yv.w * M[(size_t)(f + 3) * (FF + 1)];

#pragma unroll
    for (int off = 32; off > 0; off >>= 1) s += __shfl_down(s, off, 64);

    if (lane == 0) out[b] = 1.0f / (1.0f + expf(-s));
}

// ---------------------------------------------------------------------------
extern "C" void kernel_launch(void* const* d_in, const int* in_sizes, int n_in,
                              void* d_out, int out_size, void* d_ws, size_t ws_size,
                              hipStream_t stream) {
    const float* A    = (const float*)d_in[0];   // [R,N,N]
    const float* feat = (const float*)d_in[1];   // [N,F]
    const float* c    = (const float*)d_in[2];   // [R,N,1]
    const float* W1   = (const float*)d_in[3];   // [R,F,F]
    const float* W2   = (const float*)d_in[4];   // [R,F,F]
    const float* relm = (const float*)d_in[5];   // [R,F,F]
    const int*   e1   = (const int*)d_in[6];     // [B]
    const int*   rel  = (const int*)d_in[7];     // [B]
    const int*   e2   = (const int*)d_in[8];     // [B]
    float* out = (float*)d_out;                  // [B]

    const size_t GTh   = (size_t)RR * FF * NN;          // halves in Ght/Glt
    const size_t AEls  = (size_t)RR * NN * NN;          // elements in Ah/Al
    // fast path: Ah(256MB) + Al(256MB) + Ght/Glt(33.6MB) + P16(64MB) + H(4MB)
    const size_t fast_need = AEls * 2 * sizeof(half_t)
                           + GTh * 2 * sizeof(half_t)
                           + (size_t)16 * NN * FF * sizeof(float)
                           + (size_t)NN * FF * sizeof(float);

    dim3 gg(FF / 64, NN / 64, RR);       // (4, 64, 8)  = 2048 blocks
    const int gr = (NN * FF / 4) / 256;  // 1024 blocks

    if (ws_size >= fast_need) {
        half_t* Ah  = (half_t*)d_ws;
        half_t* Al  = Ah + AEls;
        half_t* Ght = Al + AEls;
        half_t* Glt = Ght + GTh;
        float*  P   = (float*)(Glt + GTh);
        float*  H   = P + (size_t)16 * NN * FF;

        split_a<<<2048, 256, 0, stream>>>(A, Ah, Al);
        // Layer 1
        gemm_g      <<<gg, 256, 0, stream>>>(feat, W1, Ght, Glt);
        gemm_ag_fast<<<1024, 256, 0, stream>>>(Ah, Al, Ght, Glt, c, P);
        reduce_p    <<<gr, 256, 0, stream>>>(P, H, 16);
        // Layer 2
        gemm_g      <<<gg, 256, 0, stream>>>(H, W2, Ght, Glt);
        gemm_ag_fast<<<1024, 256, 0, stream>>>(Ah, Al, Ght, Glt, c, P);
        reduce_p    <<<gr, 256, 0, stream>>>(P, H, 16);
        // Scoring
        score_k<<<BQ / 4, 256, 0, stream>>>(H, relm, e1, rel, e2, out);
    } else {
        // fallback: verified round-1 pipeline (~71 MB workspace)
        half_t* Ght = (half_t*)d_ws;
        half_t* Glt = Ght + GTh;
        float*  P   = (float*)(Glt + GTh);
        float*  H   = P + (size_t)RR * NN * FF;

        dim3 ga(FF / 128, NN / 128, RR); // (2, 32, 8) = 512 blocks
        // Layer 1
        gemm_g <<<gg, 256, 0, stream>>>(feat, W1, Ght, Glt);
        gemm_ag<<<ga, 256, 0, stream>>>(A, Ght, Glt, c, P);
        reduce_p<<<gr, 256, 0, stream>>>(P, H, RR);
        // Layer 2
        gemm_g <<<gg, 256, 0, stream>>>(H, W2, Ght, Glt);
        gemm_ag<<<ga, 256, 0, stream>>>(A, Ght, Glt, c, P);
        reduce_p<<<gr, 256, 0, stream>>>(P, H, RR);
        // Scoring
        score_k<<<BQ / 4, 256, 0, stream>>>(H, relm, e1, rel, e2, out);
    }
}